// Round 1
// baseline (226.079 us; speedup 1.0000x reference)
//
#include <hip/hip_runtime.h>
#include <hip/hip_bf16.h>

typedef __attribute__((ext_vector_type(8))) short bf16x8;
typedef __attribute__((ext_vector_type(4))) float f32x4;
typedef __attribute__((ext_vector_type(4))) short short4v;

#define HW_ 25600
#define HP_ 162
#define WP_ 162

__device__ __forceinline__ unsigned short f2bf(float f) {
    union { float f; unsigned u; } x; x.f = f;
    unsigned r = x.u + 0x7FFFu + ((x.u >> 16) & 1u);
    return (unsigned short)(r >> 16);
}

// ---------------- w_iam (100,256,3,3) -> wprep[128][9*256] bf16 (zero-padded masks)
__global__ __launch_bounds__(256) void k_prepw(const float* __restrict__ w_iam,
                                               unsigned short* __restrict__ wp) {
    int idx = blockIdx.x * 256 + threadIdx.x;
    if (idx >= 128 * 2304) return;
    int m = idx / 2304;
    int r = idx - m * 2304;
    int tap = r >> 8, c = r & 255;
    int dy = tap / 3, dx = tap - dy * 3;
    float v = 0.f;
    if (m < 100) v = w_iam[((m * 256 + c) * 3 + dy) * 3 + dx];
    wp[idx] = f2bf(v);
}

// ---------------- zero the 1-pixel border of padded NHWC buffer
__global__ __launch_bounds__(256) void k_border(unsigned short* __restrict__ fpad) {
    int idx = blockIdx.x * 256 + threadIdx.x;
    const int perb = 164864;                // 2*162*256 + 2*160*256
    if (idx >= 4 * perb) return;
    int b = idx / perb;
    int r = idx - b * perb;
    int hp, wpp, c;
    if (r < 82944) {
        hp = (r < 41472) ? 0 : 161;
        int r2 = r % 41472;
        wpp = r2 >> 8; c = r2 & 255;
    } else {
        r -= 82944;
        wpp = (r < 40960) ? 0 : 161;
        int r2 = r % 40960;
        hp = 1 + (r2 >> 8); c = r2 & 255;
    }
    fpad[((b * HP_ + hp) * WP_ + wpp) * 256 + c] = 0;
}

// ---------------- features NCHW fp32 -> fpad[b][h+1][w+1][c] bf16 (transpose via LDS)
__global__ __launch_bounds__(256) void k_convert(const float* __restrict__ feat,
                                                 unsigned short* __restrict__ fpad) {
    int bid = blockIdx.x;
    int b = bid / 640;
    int h = (bid / 4) % 160;
    int cq = bid & 3;
    int c0 = cq * 64;
    __shared__ float tile[64][161];
    int t = threadIdx.x;
    const float* src = feat + ((long)(b * 256 + c0) * 160 + h) * 160;
    for (int s = 0; s < 40; ++s) {
        int q = t + s * 256;               // 0..10239
        int ci = q / 160;
        int w = q - ci * 160;
        tile[ci][w] = src[(long)ci * HW_ + w];
    }
    __syncthreads();
    int cg = t & 15, wq = t >> 4;
    int coff = cg * 4;
    unsigned short* dstbase = fpad + ((long)(b * HP_ + h + 1) * WP_ + 1) * 256 + c0 + coff;
    for (int wp = 0; wp < 10; ++wp) {
        int w = wq + wp * 16;
        short4v v;
        v.x = (short)f2bf(tile[coff + 0][w]);
        v.y = (short)f2bf(tile[coff + 1][w]);
        v.z = (short)f2bf(tile[coff + 2][w]);
        v.w = (short)f2bf(tile[coff + 3][w]);
        *(short4v*)(dstbase + (long)w * 256) = v;
    }
}

// ---------------- conv as implicit-im2col GEMM: 128 pixels x 128 masks, K=9*256
__global__ __launch_bounds__(256, 2) void k_conv(const unsigned short* __restrict__ fpad,
                                                 const unsigned short* __restrict__ wprep,
                                                 const float* __restrict__ b_iam,
                                                 float* __restrict__ iam) {
    int bid = blockIdx.x;
    int b = bid / 200;
    int p0 = (bid % 200) * 128;
    int tid = threadIdx.x;
    int lane = tid & 63, wid = tid >> 6;
    int wr = wid >> 1, wc = wid & 1;

    __shared__ __align__(16) char smem[128 * 132 * 4];   // 67584 B
    unsigned short* A  = (unsigned short*)smem;           // [128][72]
    unsigned short* Bl = A + 128 * 72;                    // [128][72]
    float* outT = (float*)smem;                           // [128 masks][132] pixels

    int iA[4], j0A[4], hA[4], wA[4];
    for (int s = 0; s < 4; ++s) {
        int q = tid + s * 256;
        int i = q >> 3;
        iA[s] = i; j0A[s] = (q & 7) * 8;
        int p = p0 + i;
        hA[s] = p / 160;
        wA[s] = p - hA[s] * 160;
    }
    const unsigned short* fb = fpad + (long)b * HP_ * WP_ * 256;

    f32x4 acc[4][4];
    for (int i = 0; i < 4; ++i)
        for (int j = 0; j < 4; ++j)
            for (int k = 0; k < 4; ++k) acc[i][j][k] = 0.f;

    int arow = wr * 64 + (lane & 15);
    int brow = wc * 64 + (lane & 15);
    int kgrp = (lane >> 4) << 3;

    #pragma unroll
    for (int tap = 0; tap < 9; ++tap) {
        int dy = tap / 3, dx = tap - (tap / 3) * 3;
        #pragma unroll
        for (int cc = 0; cc < 4; ++cc) {
            int c0 = cc * 64;
            #pragma unroll
            for (int s = 0; s < 4; ++s) {
                const unsigned short* srcp =
                    fb + ((long)((hA[s] + dy) * WP_) + (wA[s] + dx)) * 256 + c0 + j0A[s];
                *(bf16x8*)(A + iA[s] * 72 + j0A[s]) = *(const bf16x8*)srcp;
            }
            int kw = tap * 256 + c0;
            #pragma unroll
            for (int s = 0; s < 4; ++s) {
                int q = tid + s * 256;
                int mi = q >> 3, j0 = (q & 7) * 8;
                *(bf16x8*)(Bl + mi * 72 + j0) = *(const bf16x8*)(wprep + mi * 2304 + kw + j0);
            }
            __syncthreads();
            #pragma unroll
            for (int kk = 0; kk < 64; kk += 32) {
                bf16x8 af[4], bfv[4];
                #pragma unroll
                for (int mf = 0; mf < 4; ++mf)
                    af[mf] = *(const bf16x8*)(A + (arow + mf * 16) * 72 + kk + kgrp);
                #pragma unroll
                for (int nf = 0; nf < 4; ++nf)
                    bfv[nf] = *(const bf16x8*)(Bl + (brow + nf * 16) * 72 + kk + kgrp);
                #pragma unroll
                for (int mf = 0; mf < 4; ++mf)
                    #pragma unroll
                    for (int nf = 0; nf < 4; ++nf)
                        acc[mf][nf] = __builtin_amdgcn_mfma_f32_16x16x32_bf16(
                            af[mf], bfv[nf], acc[mf][nf], 0, 0, 0);
            }
            __syncthreads();
        }
    }
    // transpose accumulators through LDS so iam writes are coalesced
    #pragma unroll
    for (int mf = 0; mf < 4; ++mf)
        #pragma unroll
        for (int nf = 0; nf < 4; ++nf) {
            int col  = wc * 64 + nf * 16 + (lane & 15);        // mask
            int row0 = wr * 64 + mf * 16 + ((lane >> 4) << 2); // pixel
            *(f32x4*)(outT + col * 132 + row0) = acc[mf][nf];
        }
    __syncthreads();
    float* dst = iam + (long)b * (100 * HW_) + p0;
    for (int q = tid; q < 100 * 32; q += 256) {
        int mrow = q >> 5, seg = q & 31;
        f32x4 v = *(const f32x4*)(outT + mrow * 132 + seg * 4);
        float bi = b_iam[mrow];
        v[0] += bi; v[1] += bi; v[2] += bi; v[3] += bi;
        *(f32x4*)(dst + (long)mrow * HW_ + seg * 4) = v;
    }
}

// ---------------- per-(b,m) online max + sumexp over HW
__global__ __launch_bounds__(256) void k_rowstats(const float* __restrict__ iam,
                                                  float* __restrict__ mx,
                                                  float* __restrict__ sm) {
    int row = blockIdx.x;                       // 0..399
    const float4* src = (const float4*)(iam + (long)row * HW_);
    int t = threadIdx.x;
    float m = -1e30f, s = 0.f;
    for (int i = t; i < 6400; i += 256) {
        float4 v = src[i];
        float vals[4] = {v.x, v.y, v.z, v.w};
        #pragma unroll
        for (int j = 0; j < 4; ++j) {
            float x = vals[j];
            if (x > m) { s = s * __expf(m - x) + 1.f; m = x; }
            else       { s += __expf(x - m); }
        }
    }
    #pragma unroll
    for (int off = 1; off < 64; off <<= 1) {
        float mo = __shfl_xor(m, off);
        float so = __shfl_xor(s, off);
        float M = fmaxf(m, mo);
        s = s * __expf(m - M) + so * __expf(mo - M);
        m = M;
    }
    __shared__ float wm[4], wsv[4];
    if ((t & 63) == 0) { wm[t >> 6] = m; wsv[t >> 6] = s; }
    __syncthreads();
    if (t == 0) {
        float M = wm[0], S = wsv[0];
        for (int w = 1; w < 4; ++w) {
            float M2 = fmaxf(M, wm[w]);
            S = S * __expf(M - M2) + wsv[w] * __expf(wm[w] - M2);
            M = M2;
        }
        mx[row] = M; sm[row] = S;
    }
}

// ---------------- split-K pooling: partials[b][slice][112][256] = exp(iam-mx) @ feat^T
__global__ __launch_bounds__(256, 2) void k_pool(const float* __restrict__ feat,
                                                 const float* __restrict__ iam,
                                                 const float* __restrict__ mx,
                                                 float* __restrict__ partials) {
    int bid = blockIdx.x;
    int b = bid / 50;
    int slice = bid % 50;
    int p0 = slice * 512;
    int tid = threadIdx.x, lane = tid & 63, wq = tid >> 6;

    __shared__ __align__(16) unsigned short A[128 * 72];
    __shared__ __align__(16) unsigned short Bl[256 * 72];

    f32x4 acc[7][4];
    for (int i = 0; i < 7; ++i)
        for (int j = 0; j < 4; ++j)
            for (int k = 0; k < 4; ++k) acc[i][j][k] = 0.f;

    int kgrp = (lane >> 4) << 3;

    for (int ks = 0; ks < 8; ++ks) {
        int k0 = p0 + ks * 64;
        // A: exp probabilities (bf16), masks padded to 128
        for (int s = 0; s < 4; ++s) {
            int q = tid + s * 256;
            int mi = q >> 3, j0 = (q & 7) * 8;
            bf16x8 o;
            if (mi < 100) {
                int row = b * 100 + mi;
                const float4* sp4 = (const float4*)(iam + (long)row * HW_ + k0 + j0);
                float4 v0 = sp4[0], v1 = sp4[1];
                float mxv = mx[row];
                float xv[8] = {v0.x, v0.y, v0.z, v0.w, v1.x, v1.y, v1.z, v1.w};
                #pragma unroll
                for (int j = 0; j < 8; ++j) o[j] = (short)f2bf(__expf(xv[j] - mxv));
            } else {
                #pragma unroll
                for (int j = 0; j < 8; ++j) o[j] = 0;
            }
            *(bf16x8*)(A + mi * 72 + j0) = o;
        }
        // B: features (NCHW fp32 -> bf16), rows = channels, cols = pixels
        for (int s = 0; s < 8; ++s) {
            int q = tid + s * 256;
            int ci = q >> 3, j0 = (q & 7) * 8;
            const float4* sp4 = (const float4*)(feat + (long)(b * 256 + ci) * HW_ + k0 + j0);
            float4 v0 = sp4[0], v1 = sp4[1];
            float xv[8] = {v0.x, v0.y, v0.z, v0.w, v1.x, v1.y, v1.z, v1.w};
            bf16x8 o;
            #pragma unroll
            for (int j = 0; j < 8; ++j) o[j] = (short)f2bf(xv[j]);
            *(bf16x8*)(Bl + ci * 72 + j0) = o;
        }
        __syncthreads();
        #pragma unroll
        for (int kk = 0; kk < 64; kk += 32) {
            bf16x8 af[7], bfv[4];
            #pragma unroll
            for (int mf = 0; mf < 7; ++mf)
                af[mf] = *(const bf16x8*)(A + (mf * 16 + (lane & 15)) * 72 + kk + kgrp);
            #pragma unroll
            for (int nf = 0; nf < 4; ++nf)
                bfv[nf] = *(const bf16x8*)(Bl + (wq * 64 + nf * 16 + (lane & 15)) * 72 + kk + kgrp);
            #pragma unroll
            for (int mf = 0; mf < 7; ++mf)
                #pragma unroll
                for (int nf = 0; nf < 4; ++nf)
                    acc[mf][nf] = __builtin_amdgcn_mfma_f32_16x16x32_bf16(
                        af[mf], bfv[nf], acc[mf][nf], 0, 0, 0);
        }
        __syncthreads();
    }
    float* dst = partials + (long)(b * 50 + slice) * 112 * 256;
    #pragma unroll
    for (int mf = 0; mf < 7; ++mf)
        #pragma unroll
        for (int nf = 0; nf < 4; ++nf) {
            int m0 = mf * 16 + ((lane >> 4) << 2);
            int c  = wq * 64 + nf * 16 + (lane & 15);
            #pragma unroll
            for (int j = 0; j < 4; ++j)
                dst[(long)(m0 + j) * 256 + c] = acc[mf][nf][j];
        }
}

// ---------------- sum partial slices, divide by sumexp -> inst_pool
__global__ __launch_bounds__(256) void k_redpool(const float* __restrict__ partials,
                                                 const float* __restrict__ sm,
                                                 float* __restrict__ inst_pool) {
    int bid = blockIdx.x;                       // b*100+m
    int b = bid / 100, m = bid - b * 100;
    int c = threadIdx.x;
    float s = 0.f;
    for (int sl = 0; sl < 50; ++sl)
        s += partials[((long)(b * 50 + sl) * 112 + m) * 256 + c];
    inst_pool[(long)bid * 256 + c] = s / sm[bid];
}

// ---------------- fc + relu + 4 heads (all fp32)
__global__ __launch_bounds__(256) void k_fc(const float* __restrict__ inst_pool,
                                            const float* __restrict__ w_fc, const float* __restrict__ b_fc,
                                            const float* __restrict__ w_cls, const float* __restrict__ b_cls,
                                            const float* __restrict__ w_ker, const float* __restrict__ b_ker,
                                            const float* __restrict__ w_obj, const float* __restrict__ b_obj,
                                            const float* __restrict__ w_box, const float* __restrict__ b_box,
                                            float* __restrict__ out) {
    int r = blockIdx.x;                         // 0..399
    int t = threadIdx.x;
    __shared__ float row[256];
    __shared__ float inst_s[256];
    row[t] = inst_pool[(long)r * 256 + t];
    __syncthreads();
    {
        float acc = b_fc[t];
        const float4* wv = (const float4*)(w_fc + (long)t * 256);
        for (int c = 0; c < 64; ++c) {
            float4 w4 = wv[c];
            acc += w4.x * row[c * 4] + w4.y * row[c * 4 + 1] + w4.z * row[c * 4 + 2] + w4.w * row[c * 4 + 3];
        }
        acc = fmaxf(acc, 0.f);
        inst_s[t] = acc;
        out[10376800 + (long)r * 256 + t] = acc;   // inst
    }
    __syncthreads();
    {
        float acc = b_ker[t];
        const float4* wv = (const float4*)(w_ker + (long)t * 256);
        for (int c = 0; c < 64; ++c) {
            float4 w4 = wv[c];
            acc += w4.x * inst_s[c * 4] + w4.y * inst_s[c * 4 + 1] + w4.z * inst_s[c * 4 + 2] + w4.w * inst_s[c * 4 + 3];
        }
        out[32400 + (long)r * 256 + t] = acc;      // pred_kernel
    }
    if (t < 81) {
        float acc = b_cls[t];
        const float4* wv = (const float4*)(w_cls + (long)t * 256);
        for (int c = 0; c < 64; ++c) {
            float4 w4 = wv[c];
            acc += w4.x * inst_s[c * 4] + w4.y * inst_s[c * 4 + 1] + w4.z * inst_s[c * 4 + 2] + w4.w * inst_s[c * 4 + 3];
        }
        out[(long)r * 81 + t] = acc;               // pred_logits
    }
    if (t == 0) {
        float acc = b_obj[0];
        for (int c = 0; c < 256; ++c) acc += w_obj[c] * inst_s[c];
        out[134800 + r] = acc;                     // pred_scores
    }
    if (t >= 1 && t < 5) {
        int j = t - 1;
        float acc = b_box[j];
        for (int c = 0; c < 256; ++c) acc += w_box[j * 256 + c] * inst_s[c];
        out[135200 + (long)r * 4 + j] = acc;       // pred_bboxes
    }
}

extern "C" void kernel_launch(void* const* d_in, const int* in_sizes, int n_in,
                              void* d_out, int out_size, void* d_ws, size_t ws_size,
                              hipStream_t stream) {
    const float* feat  = (const float*)d_in[0];
    const float* w_iam = (const float*)d_in[1];
    const float* b_iam = (const float*)d_in[2];
    // d_in[3] softmax_bias: uniform shift inside softmax -> cancels exactly
    const float* w_fc  = (const float*)d_in[4];
    const float* b_fc  = (const float*)d_in[5];
    const float* w_cls = (const float*)d_in[6];
    const float* b_cls = (const float*)d_in[7];
    const float* w_ker = (const float*)d_in[8];
    const float* b_ker = (const float*)d_in[9];
    const float* w_obj = (const float*)d_in[10];
    const float* b_obj = (const float*)d_in[11];
    const float* w_box = (const float*)d_in[12];
    const float* b_box = (const float*)d_in[13];
    float* out = (float*)d_out;

    char* ws = (char*)d_ws;
    unsigned short* fpad  = (unsigned short*)ws;               // 53,747,712 B
    unsigned short* wprep = (unsigned short*)(ws + 53747712);  //    589,824 B
    float* mx        = (float*)(ws + 54337536);                //      1,600 B
    float* sme       = (float*)(ws + 54339136);                //      1,600 B
    float* inst_pool = (float*)(ws + 54340736);                //    409,600 B
    float* partials  = (float*)ws;                             // alias fpad (dead after conv)

    float* iam = out + 136800;

    k_prepw  <<<dim3(1152), dim3(256), 0, stream>>>(w_iam, wprep);
    k_border <<<dim3(2576), dim3(256), 0, stream>>>(fpad);
    k_convert<<<dim3(2560), dim3(256), 0, stream>>>(feat, fpad);
    k_conv   <<<dim3(800),  dim3(256), 0, stream>>>(fpad, wprep, b_iam, iam);
    k_rowstats<<<dim3(400), dim3(256), 0, stream>>>(iam, mx, sme);
    k_pool   <<<dim3(200),  dim3(256), 0, stream>>>(feat, iam, mx, partials);
    k_redpool<<<dim3(400),  dim3(256), 0, stream>>>(partials, sme, inst_pool);
    k_fc     <<<dim3(400),  dim3(256), 0, stream>>>(inst_pool, w_fc, b_fc, w_cls, b_cls,
                                                    w_ker, b_ker, w_obj, b_obj, w_box, b_box, out);
}

// Round 3
// 205.222 us; speedup vs baseline: 1.1016x; 1.1016x over previous
//
#include <hip/hip_runtime.h>
#include <hip/hip_bf16.h>

typedef __attribute__((ext_vector_type(8))) short bf16x8;
typedef __attribute__((ext_vector_type(4))) float f32x4;

#define HW_ 25600
#define HP_ 162
#define WP_ 162

__device__ __forceinline__ unsigned short f2bf(float f) {
    union { float f; unsigned u; } x; x.f = f;
    unsigned r = x.u + 0x7FFFu + ((x.u >> 16) & 1u);
    return (unsigned short)(r >> 16);
}

typedef const __attribute__((address_space(1))) unsigned int* gas_t;
typedef __attribute__((address_space(3))) unsigned int* las_t;
__device__ __forceinline__ void gl_lds16(const void* g, void* l) {
    __builtin_amdgcn_global_load_lds((gas_t)g, (las_t)l, 16, 0, 0);
}

// ---------------- w_iam (100,256,3,3) -> wprep[36 stages][128 masks][64 ch] bf16
__global__ __launch_bounds__(256) void k_prepw(const float* __restrict__ w_iam,
                                               unsigned short* __restrict__ wp) {
    int idx = blockIdx.x * 256 + threadIdx.x;
    if (idx >= 36 * 8192) return;
    int stage = idx >> 13;
    int r8 = idx & 8191;
    int m = r8 >> 6, cl = r8 & 63;
    int tap = stage >> 2, cc = stage & 3;
    int c = cc * 64 + cl;
    int dy = tap / 3, dx = tap - dy * 3;
    float v = (m < 100) ? w_iam[((m * 256 + c) * 3 + dy) * 3 + dx] : 0.f;
    wp[idx] = f2bf(v);
}

// ---------------- zero the 1-pixel border of padded NHWC buffer
__global__ __launch_bounds__(256) void k_border(unsigned short* __restrict__ fpad) {
    int idx = blockIdx.x * 256 + threadIdx.x;
    const int perb = 164864;
    if (idx >= 4 * perb) return;
    int b = idx / perb;
    int r = idx - b * perb;
    int hp, wpp, c;
    if (r < 82944) {
        hp = (r < 41472) ? 0 : 161;
        int r2 = r % 41472;
        wpp = r2 >> 8; c = r2 & 255;
    } else {
        r -= 82944;
        wpp = (r < 40960) ? 0 : 161;
        int r2 = r % 40960;
        hp = 1 + (r2 >> 8); c = r2 & 255;
    }
    fpad[((b * HP_ + hp) * WP_ + wpp) * 256 + c] = 0;
}

// ---------------- features NCHW fp32 -> fpad[b][h+1][w+1][c] bf16 (LDS transpose, 16B stores)
__global__ __launch_bounds__(256) void k_convert(const float* __restrict__ feat,
                                                 unsigned short* __restrict__ fpad) {
    int bid = blockIdx.x;
    int b = bid / 640;
    int h = (bid >> 2) % 160;
    int c0 = (bid & 3) * 64;
    __shared__ float tile[64][161];
    int t = threadIdx.x;
    const float* src = feat + ((long)(b * 256 + c0) * 160 + h) * 160;
    for (int s = 0; s < 40; ++s) {
        int q = t + s * 256;
        int ci = q / 160;
        int w = q - ci * 160;
        tile[ci][w] = src[(long)ci * HW_ + w];
    }
    __syncthreads();
    int co = (t & 7) * 8, wq = t >> 3;
    unsigned short* dst = fpad + ((long)(b * HP_ + h + 1) * WP_ + 1) * 256 + c0 + co;
    for (int wp = 0; wp < 5; ++wp) {
        int w = wq + wp * 32;
        bf16x8 v;
        #pragma unroll
        for (int j = 0; j < 8; ++j) v[j] = (short)f2bf(tile[co + j][w]);
        *(bf16x8*)(dst + (long)w * 256) = v;
    }
}

// ---------------- conv GEMM: C[112 masks][128 pixels], K=2304, global_load_lds staging
__global__ __launch_bounds__(256, 4) void k_conv(const unsigned short* __restrict__ fpad,
                                                 const unsigned short* __restrict__ wprep,
                                                 const float* __restrict__ b_iam,
                                                 float* __restrict__ iam) {
    int bid = blockIdx.x;
    bid = (bid & 7) * 100 + (bid >> 3);          // XCD swizzle (800 % 8 == 0, bijective)
    int b = bid / 200;
    int p0 = (bid % 200) * 128;
    int tid = threadIdx.x;
    int lane = tid & 63, wid = tid >> 6;

    __shared__ __align__(16) unsigned short As[128 * 64];   // masks x 64ch
    __shared__ __align__(16) unsigned short Bs[128 * 64];   // pixels x 64ch

    // per-round B global bases. Output pixel (h,w), tap (dy,dx) reads padded
    // coords (h+dy, w+dx)  [pad shift +1 means base is (h,w), NOT (h+1,w+1)].
    const unsigned short* fb = fpad + (long)b * HP_ * WP_ * 256;
    const unsigned short* gB[4];
    #pragma unroll
    for (int rnd = 0; rnd < 4; ++rnd) {
        int r = (tid >> 3) + rnd * 32;
        int p = p0 + r;
        int h = p / 160, w = p - h * 160;
        gB[rnd] = fb + ((long)h * WP_ + w) * 256 + (tid & 7) * 8;
    }

    f32x4 acc[7][2];
    #pragma unroll
    for (int i = 0; i < 7; ++i)
        #pragma unroll
        for (int j = 0; j < 2; ++j)
            #pragma unroll
            for (int k = 0; k < 4; ++k) acc[i][j][k] = 0.f;

    int kgrp = (lane >> 4) << 3;
    int arow = lane & 15;

    for (int tap = 0; tap < 9; ++tap) {
        int dy = tap / 3, dx = tap - dy * 3;
        long toff = ((long)dy * WP_ + dx) * 256;
        #pragma unroll
        for (int cc = 0; cc < 4; ++cc) {
            int stage = tap * 4 + cc;
            const unsigned short* ga = wprep + (long)stage * 8192 + (tid << 3);
            long boff = toff + cc * 64;
            #pragma unroll
            for (int rnd = 0; rnd < 4; ++rnd) {
                gl_lds16(ga + rnd * 2048, (char*)As + (wid << 10) + (rnd << 12));
                gl_lds16(gB[rnd] + boff, (char*)Bs + (wid << 10) + (rnd << 12));
            }
            __syncthreads();
            #pragma unroll
            for (int kk = 0; kk < 64; kk += 32) {
                bf16x8 af[7], bfv[2];
                #pragma unroll
                for (int mf = 0; mf < 7; ++mf)
                    af[mf] = *(const bf16x8*)(As + (mf * 16 + arow) * 64 + kk + kgrp);
                #pragma unroll
                for (int nf = 0; nf < 2; ++nf)
                    bfv[nf] = *(const bf16x8*)(Bs + (wid * 32 + nf * 16 + arow) * 64 + kk + kgrp);
                #pragma unroll
                for (int mf = 0; mf < 7; ++mf)
                    #pragma unroll
                    for (int nf = 0; nf < 2; ++nf)
                        acc[mf][nf] = __builtin_amdgcn_mfma_f32_16x16x32_bf16(
                            af[mf], bfv[nf], acc[mf][nf], 0, 0, 0);
            }
            __syncthreads();
        }
    }
    // direct C write: D.row = mask (A operand), D.col = pixel (B operand)
    float* dst = iam + (long)b * 100 * HW_;
    #pragma unroll
    for (int mf = 0; mf < 7; ++mf)
        #pragma unroll
        for (int nf = 0; nf < 2; ++nf) {
            int p = p0 + wid * 32 + nf * 16 + (lane & 15);
            int m0 = mf * 16 + ((lane >> 4) << 2);
            #pragma unroll
            for (int j = 0; j < 4; ++j) {
                int m = m0 + j;
                if (m < 100) dst[(long)m * HW_ + p] = acc[mf][nf][j] + b_iam[m];
            }
        }
}

// ---------------- split-K pooling (no max shift): partials[b][sl][112][256], psum[b][sl][112]
__global__ __launch_bounds__(256, 2) void k_pool(const float* __restrict__ feat,
                                                 const float* __restrict__ iam,
                                                 float* __restrict__ partials,
                                                 float* __restrict__ psum) {
    int bid = blockIdx.x;
    int b = bid / 50;
    int slice = bid - b * 50;
    int p0 = slice * 512;
    int tid = threadIdx.x, lane = tid & 63, wq = tid >> 6;

    __shared__ __align__(16) unsigned short A[128 * 72];
    __shared__ __align__(16) unsigned short Bl[256 * 72];
    __shared__ float sums[128];
    if (tid < 128) sums[tid] = 0.f;
    __syncthreads();

    f32x4 acc[7][4];
    #pragma unroll
    for (int i = 0; i < 7; ++i)
        #pragma unroll
        for (int j = 0; j < 4; ++j)
            #pragma unroll
            for (int k = 0; k < 4; ++k) acc[i][j][k] = 0.f;

    int kgrp = (lane >> 4) << 3;

    for (int ks = 0; ks < 8; ++ks) {
        int k0 = p0 + ks * 64;
        // A: exp(iam) bf16, masks padded to 128; accumulate row sums in LDS
        for (int s = 0; s < 4; ++s) {
            int q = tid + s * 256;
            int mi = q >> 3, j0 = (q & 7) * 8;
            bf16x8 o;
            if (mi < 100) {
                const float4* sp4 = (const float4*)(iam + (long)(b * 100 + mi) * HW_ + k0 + j0);
                float4 v0 = sp4[0], v1 = sp4[1];
                float xv[8] = {v0.x, v0.y, v0.z, v0.w, v1.x, v1.y, v1.z, v1.w};
                float ls = 0.f;
                #pragma unroll
                for (int j = 0; j < 8; ++j) {
                    float e = __expf(xv[j]);
                    o[j] = (short)f2bf(e);
                    ls += e;
                }
                atomicAdd(&sums[mi], ls);
            } else {
                #pragma unroll
                for (int j = 0; j < 8; ++j) o[j] = 0;
            }
            *(bf16x8*)(A + mi * 72 + j0) = o;
        }
        // B: features (NCHW fp32 -> bf16), rows = channels
        for (int s = 0; s < 8; ++s) {
            int q = tid + s * 256;
            int ci = q >> 3, j0 = (q & 7) * 8;
            const float4* sp4 = (const float4*)(feat + (long)(b * 256 + ci) * HW_ + k0 + j0);
            float4 v0 = sp4[0], v1 = sp4[1];
            float xv[8] = {v0.x, v0.y, v0.z, v0.w, v1.x, v1.y, v1.z, v1.w};
            bf16x8 o;
            #pragma unroll
            for (int j = 0; j < 8; ++j) o[j] = (short)f2bf(xv[j]);
            *(bf16x8*)(Bl + ci * 72 + j0) = o;
        }
        __syncthreads();
        #pragma unroll
        for (int kk = 0; kk < 64; kk += 32) {
            bf16x8 af[7], bfv[4];
            #pragma unroll
            for (int mf = 0; mf < 7; ++mf)
                af[mf] = *(const bf16x8*)(A + (mf * 16 + (lane & 15)) * 72 + kk + kgrp);
            #pragma unroll
            for (int nf = 0; nf < 4; ++nf)
                bfv[nf] = *(const bf16x8*)(Bl + (wq * 64 + nf * 16 + (lane & 15)) * 72 + kk + kgrp);
            #pragma unroll
            for (int mf = 0; mf < 7; ++mf)
                #pragma unroll
                for (int nf = 0; nf < 4; ++nf)
                    acc[mf][nf] = __builtin_amdgcn_mfma_f32_16x16x32_bf16(
                        af[mf], bfv[nf], acc[mf][nf], 0, 0, 0);
        }
        __syncthreads();
    }
    if (tid < 100) psum[(long)(b * 50 + slice) * 112 + tid] = sums[tid];
    float* dst = partials + (long)(b * 50 + slice) * 112 * 256;
    #pragma unroll
    for (int mf = 0; mf < 7; ++mf)
        #pragma unroll
        for (int nf = 0; nf < 4; ++nf) {
            int m0 = mf * 16 + ((lane >> 4) << 2);
            int c  = wq * 64 + nf * 16 + (lane & 15);
            #pragma unroll
            for (int j = 0; j < 4; ++j)
                dst[(long)(m0 + j) * 256 + c] = acc[mf][nf][j];
        }
}

// ---------------- sum partial slices + divide by denom -> inst_pool
__global__ __launch_bounds__(256) void k_redpool(const float* __restrict__ partials,
                                                 const float* __restrict__ psum,
                                                 float* __restrict__ inst_pool) {
    int bid = blockIdx.x;                       // b*100+m
    int b = bid / 100, m = bid - b * 100;
    int c = threadIdx.x;
    float s = 0.f, d = 0.f;
    for (int sl = 0; sl < 50; ++sl) {
        s += partials[((long)(b * 50 + sl) * 112 + m) * 256 + c];
        d += psum[(long)(b * 50 + sl) * 112 + m];
    }
    inst_pool[(long)bid * 256 + c] = s / d;
}

// ---------------- fc + relu + 4 heads (all fp32)
__global__ __launch_bounds__(256) void k_fc(const float* __restrict__ inst_pool,
                                            const float* __restrict__ w_fc, const float* __restrict__ b_fc,
                                            const float* __restrict__ w_cls, const float* __restrict__ b_cls,
                                            const float* __restrict__ w_ker, const float* __restrict__ b_ker,
                                            const float* __restrict__ w_obj, const float* __restrict__ b_obj,
                                            const float* __restrict__ w_box, const float* __restrict__ b_box,
                                            float* __restrict__ out) {
    int r = blockIdx.x;                         // 0..399
    int t = threadIdx.x;
    __shared__ float row[256];
    __shared__ float inst_s[256];
    row[t] = inst_pool[(long)r * 256 + t];
    __syncthreads();
    {
        float acc = b_fc[t];
        const float4* wv = (const float4*)(w_fc + (long)t * 256);
        for (int c = 0; c < 64; ++c) {
            float4 w4 = wv[c];
            acc += w4.x * row[c * 4] + w4.y * row[c * 4 + 1] + w4.z * row[c * 4 + 2] + w4.w * row[c * 4 + 3];
        }
        acc = fmaxf(acc, 0.f);
        inst_s[t] = acc;
        out[10376800 + (long)r * 256 + t] = acc;   // inst
    }
    __syncthreads();
    {
        float acc = b_ker[t];
        const float4* wv = (const float4*)(w_ker + (long)t * 256);
        for (int c = 0; c < 64; ++c) {
            float4 w4 = wv[c];
            acc += w4.x * inst_s[c * 4] + w4.y * inst_s[c * 4 + 1] + w4.z * inst_s[c * 4 + 2] + w4.w * inst_s[c * 4 + 3];
        }
        out[32400 + (long)r * 256 + t] = acc;      // pred_kernel
    }
    if (t < 81) {
        float acc = b_cls[t];
        const float4* wv = (const float4*)(w_cls + (long)t * 256);
        for (int c = 0; c < 64; ++c) {
            float4 w4 = wv[c];
            acc += w4.x * inst_s[c * 4] + w4.y * inst_s[c * 4 + 1] + w4.z * inst_s[c * 4 + 2] + w4.w * inst_s[c * 4 + 3];
        }
        out[(long)r * 81 + t] = acc;               // pred_logits
    }
    if (t == 0) {
        float acc = b_obj[0];
        for (int c = 0; c < 256; ++c) acc += w_obj[c] * inst_s[c];
        out[134800 + r] = acc;                     // pred_scores
    }
    if (t >= 1 && t < 5) {
        int j = t - 1;
        float acc = b_box[j];
        for (int c = 0; c < 256; ++c) acc += w_box[j * 256 + c] * inst_s[c];
        out[135200 + (long)r * 4 + j] = acc;       // pred_bboxes
    }
}

extern "C" void kernel_launch(void* const* d_in, const int* in_sizes, int n_in,
                              void* d_out, int out_size, void* d_ws, size_t ws_size,
                              hipStream_t stream) {
    const float* feat  = (const float*)d_in[0];
    const float* w_iam = (const float*)d_in[1];
    const float* b_iam = (const float*)d_in[2];
    // d_in[3] softmax_bias: uniform shift inside softmax -> cancels exactly
    const float* w_fc  = (const float*)d_in[4];
    const float* b_fc  = (const float*)d_in[5];
    const float* w_cls = (const float*)d_in[6];
    const float* b_cls = (const float*)d_in[7];
    const float* w_ker = (const float*)d_in[8];
    const float* b_ker = (const float*)d_in[9];
    const float* w_obj = (const float*)d_in[10];
    const float* b_obj = (const float*)d_in[11];
    const float* w_box = (const float*)d_in[12];
    const float* b_box = (const float*)d_in[13];
    float* out = (float*)d_out;

    char* ws = (char*)d_ws;
    unsigned short* fpad  = (unsigned short*)ws;               // 53,747,712 B
    unsigned short* wprep = (unsigned short*)(ws + 53747712);  //    589,824 B -> end 54,337,536
    // post-conv phase aliases fpad (dead after k_conv):
    float* partials  = (float*)ws;                             // 22,937,600 B
    float* psum      = (float*)(ws + 22937600);                //     89,600 B
    float* inst_pool = (float*)(ws + 23027200);                //    409,600 B

    float* iam = out + 136800;

    k_prepw  <<<dim3(1152), dim3(256), 0, stream>>>(w_iam, wprep);
    k_border <<<dim3(2576), dim3(256), 0, stream>>>(fpad);
    k_convert<<<dim3(2560), dim3(256), 0, stream>>>(feat, fpad);
    k_conv   <<<dim3(800),  dim3(256), 0, stream>>>(fpad, wprep, b_iam, iam);
    k_pool   <<<dim3(200),  dim3(256), 0, stream>>>(feat, iam, partials, psum);
    k_redpool<<<dim3(400),  dim3(256), 0, stream>>>(partials, psum, inst_pool);
    k_fc     <<<dim3(400),  dim3(256), 0, stream>>>(inst_pool, w_fc, b_fc, w_cls, b_cls,
                                                    w_ker, b_ker, w_obj, b_obj, w_box, b_box, out);
}

// Round 4
// 201.493 us; speedup vs baseline: 1.1220x; 1.0185x over previous
//
#include <hip/hip_runtime.h>
#include <hip/hip_bf16.h>

typedef __attribute__((ext_vector_type(8))) short bf16x8;
typedef __attribute__((ext_vector_type(4))) float f32x4;

#define HW_ 25600
#define HP_ 162
#define WP_ 162

__device__ __forceinline__ unsigned short f2bf(float f) {
    union { float f; unsigned u; } x; x.f = f;
    unsigned r = x.u + 0x7FFFu + ((x.u >> 16) & 1u);
    return (unsigned short)(r >> 16);
}

typedef const __attribute__((address_space(1))) unsigned int* gas_t;
typedef __attribute__((address_space(3))) unsigned int* las_t;
__device__ __forceinline__ void gl_lds16(const void* g, void* l) {
    __builtin_amdgcn_global_load_lds((gas_t)g, (las_t)l, 16, 0, 0);
}

// ---------------- w_iam (100,256,3,3) -> wprep[36 stages][128 masks][64 ch] bf16
// chunk-swizzled: storage (m, chunk j) holds logical chunk j^(m&7)  [T2 via pre-swizzled source]
__global__ __launch_bounds__(256) void k_prepw(const float* __restrict__ w_iam,
                                               unsigned short* __restrict__ wp) {
    int idx = blockIdx.x * 256 + threadIdx.x;
    if (idx >= 36 * 8192) return;
    int stage = idx >> 13;
    int r8 = idx & 8191;
    int m = r8 >> 6, cl = r8 & 63;
    int tap = stage >> 2, cc = stage & 3;
    int jj = (cl >> 3) ^ (m & 7);                 // logical chunk for this storage slot
    int c = cc * 64 + jj * 8 + (cl & 7);
    int dy = tap / 3, dx = tap - dy * 3;
    float v = (m < 100) ? w_iam[((m * 256 + c) * 3 + dy) * 3 + dx] : 0.f;
    wp[idx] = f2bf(v);
}

// ---------------- zero the 1-pixel border of padded NHWC buffer
__global__ __launch_bounds__(256) void k_border(unsigned short* __restrict__ fpad) {
    int idx = blockIdx.x * 256 + threadIdx.x;
    const int perb = 164864;
    if (idx >= 4 * perb) return;
    int b = idx / perb;
    int r = idx - b * perb;
    int hp, wpp, c;
    if (r < 82944) {
        hp = (r < 41472) ? 0 : 161;
        int r2 = r % 41472;
        wpp = r2 >> 8; c = r2 & 255;
    } else {
        r -= 82944;
        wpp = (r < 40960) ? 0 : 161;
        int r2 = r % 40960;
        hp = 1 + (r2 >> 8); c = r2 & 255;
    }
    fpad[((b * HP_ + hp) * WP_ + wpp) * 256 + c] = 0;
}

// ---------------- features NCHW fp32 -> fpad[b][h+1][w+1][c] bf16 (LDS transpose, 16B stores)
__global__ __launch_bounds__(256) void k_convert(const float* __restrict__ feat,
                                                 unsigned short* __restrict__ fpad) {
    int bid = blockIdx.x;
    int b = bid / 640;
    int h = (bid >> 2) % 160;
    int c0 = (bid & 3) * 64;
    __shared__ float tile[64][161];
    int t = threadIdx.x;
    const float* src = feat + ((long)(b * 256 + c0) * 160 + h) * 160;
    for (int s = 0; s < 40; ++s) {
        int q = t + s * 256;
        int ci = q / 160;
        int w = q - ci * 160;
        tile[ci][w] = src[(long)ci * HW_ + w];
    }
    __syncthreads();
    int co = (t & 7) * 8, wq = t >> 3;
    unsigned short* dst = fpad + ((long)(b * HP_ + h + 1) * WP_ + 1) * 256 + c0 + co;
    for (int wp = 0; wp < 5; ++wp) {
        int w = wq + wp * 32;
        bf16x8 v;
        #pragma unroll
        for (int j = 0; j < 8; ++j) v[j] = (short)f2bf(tile[co + j][w]);
        *(bf16x8*)(dst + (long)w * 256) = v;
    }
}

// ---------------- conv GEMM: C[112 masks][128 pixels], K=2304
// double-buffered LDS + counted vmcnt(8) pipeline + XOR chunk swizzle
__global__ __launch_bounds__(256) void k_conv(const unsigned short* __restrict__ fpad,
                                              const unsigned short* __restrict__ wprep,
                                              const float* __restrict__ b_iam,
                                              float* __restrict__ iam) {
    int bid = blockIdx.x;
    bid = (bid & 7) * 100 + (bid >> 3);          // XCD swizzle (800 % 8 == 0, bijective)
    int b = bid / 200;
    int p0 = (bid % 200) * 128;
    int tid = threadIdx.x;
    int lane = tid & 63, wid = tid >> 6;

    __shared__ __align__(16) unsigned short As[2][8192];   // [buf][128 masks x 64ch]
    __shared__ __align__(16) unsigned short Bs[2][8192];   // [buf][128 pixels x 64ch]

    // B staging: lane covers pixel row r=(tid>>3)+rnd*32, fetches global chunk
    // (tid&7)^(r&7) so linear LDS dest ends up chunk-swizzled (rule #21: src-permute).
    const unsigned short* fb = fpad + (long)b * HP_ * WP_ * 256;
    const unsigned short* gB[4];
    int csw = (((tid & 7) ^ ((tid >> 3) & 7)) << 3);
    #pragma unroll
    for (int rnd = 0; rnd < 4; ++rnd) {
        int r = (tid >> 3) + rnd * 32;
        int p = p0 + r;
        int h = p / 160, w = p - h * 160;
        gB[rnd] = fb + ((long)h * WP_ + w) * 256 + csw;
    }
    const unsigned short* gA0 = wprep + (tid << 3);

    f32x4 acc[7][2];
    #pragma unroll
    for (int i = 0; i < 7; ++i)
        #pragma unroll
        for (int j = 0; j < 2; ++j)
            #pragma unroll
            for (int k = 0; k < 4; ++k) acc[i][j][k] = 0.f;

    int arow = lane & 15;
    // swizzled chunk byte-offsets for the two kk steps (chunk J = kk/8 + lane>>4, XOR lane&7)
    int cs0 = ((((lane >> 4) ^ (lane & 7))) << 3);   // element offset, kk=0
    int cs1 = cs0 ^ 32;                               // kk=32 (chunk J+4 -> XOR 4 chunks)

    auto issue = [&](int s, int bi) {
        int tap = s >> 2, cc = s & 3;
        int dy = tap / 3, dx = tap - dy * 3;
        long boff = ((long)dy * WP_ + dx) * 256 + cc * 64;
        const unsigned short* ga = gA0 + ((long)s << 13);
        char* Ad = (char*)As[bi];
        char* Bd = (char*)Bs[bi];
        #pragma unroll
        for (int rnd = 0; rnd < 4; ++rnd) {
            gl_lds16(ga + (rnd << 11), Ad + (wid << 10) + (rnd << 12));
            gl_lds16(gB[rnd] + boff,   Bd + (wid << 10) + (rnd << 12));
        }
    };

    auto compute = [&](int bi) {
        const unsigned short* Ab = As[bi];
        const unsigned short* Bb = Bs[bi];
        #pragma unroll
        for (int kk = 0; kk < 2; ++kk) {
            int co = kk ? cs1 : cs0;
            bf16x8 af[7], bfv[2];
            #pragma unroll
            for (int mf = 0; mf < 7; ++mf)
                af[mf] = *(const bf16x8*)(Ab + (mf * 16 + arow) * 64 + co);
            #pragma unroll
            for (int nf = 0; nf < 2; ++nf)
                bfv[nf] = *(const bf16x8*)(Bb + (wid * 32 + nf * 16 + arow) * 64 + co);
            #pragma unroll
            for (int mf = 0; mf < 7; ++mf)
                #pragma unroll
                for (int nf = 0; nf < 2; ++nf)
                    acc[mf][nf] = __builtin_amdgcn_mfma_f32_16x16x32_bf16(
                        af[mf], bfv[nf], acc[mf][nf], 0, 0, 0);
        }
    };

    issue(0, 0);
    issue(1, 1);
    for (int s = 0; s < 35; ++s) {
        asm volatile("s_waitcnt vmcnt(8)" ::: "memory");   // stage s landed; s+1 stays in flight
        __builtin_amdgcn_sched_barrier(0);
        __builtin_amdgcn_s_barrier();
        __builtin_amdgcn_sched_barrier(0);
        compute(s & 1);
        __builtin_amdgcn_sched_barrier(0);
        __builtin_amdgcn_s_barrier();                      // all waves done reading buf[s&1]
        __builtin_amdgcn_sched_barrier(0);
        if (s < 34) issue(s + 2, s & 1);
    }
    asm volatile("s_waitcnt vmcnt(0)" ::: "memory");
    __builtin_amdgcn_sched_barrier(0);
    __builtin_amdgcn_s_barrier();
    __builtin_amdgcn_sched_barrier(0);
    compute(1);

    // direct C write: D.row = mask (A operand), D.col = pixel (B operand)
    float* dst = iam + (long)b * 100 * HW_;
    #pragma unroll
    for (int mf = 0; mf < 7; ++mf)
        #pragma unroll
        for (int nf = 0; nf < 2; ++nf) {
            int p = p0 + wid * 32 + nf * 16 + (lane & 15);
            int m0 = mf * 16 + ((lane >> 4) << 2);
            #pragma unroll
            for (int j = 0; j < 4; ++j) {
                int m = m0 + j;
                if (m < 100) dst[(long)m * HW_ + p] = acc[mf][nf][j] + b_iam[m];
            }
        }
}

// ---------------- split-K pooling (no max shift): partials[b][sl][112][256], psum[b][sl][112]
__global__ __launch_bounds__(256, 2) void k_pool(const float* __restrict__ feat,
                                                 const float* __restrict__ iam,
                                                 float* __restrict__ partials,
                                                 float* __restrict__ psum) {
    int bid = blockIdx.x;
    int b = bid / 50;
    int slice = bid - b * 50;
    int p0 = slice * 512;
    int tid = threadIdx.x, lane = tid & 63, wq = tid >> 6;

    __shared__ __align__(16) unsigned short A[128 * 72];
    __shared__ __align__(16) unsigned short Bl[256 * 72];
    __shared__ float sums[128];
    if (tid < 128) sums[tid] = 0.f;
    __syncthreads();

    f32x4 acc[7][4];
    #pragma unroll
    for (int i = 0; i < 7; ++i)
        #pragma unroll
        for (int j = 0; j < 4; ++j)
            #pragma unroll
            for (int k = 0; k < 4; ++k) acc[i][j][k] = 0.f;

    int kgrp = (lane >> 4) << 3;

    for (int ks = 0; ks < 8; ++ks) {
        int k0 = p0 + ks * 64;
        // A: exp(iam) bf16, masks padded to 128; accumulate row sums in LDS
        for (int s = 0; s < 4; ++s) {
            int q = tid + s * 256;
            int mi = q >> 3, j0 = (q & 7) * 8;
            bf16x8 o;
            if (mi < 100) {
                const float4* sp4 = (const float4*)(iam + (long)(b * 100 + mi) * HW_ + k0 + j0);
                float4 v0 = sp4[0], v1 = sp4[1];
                float xv[8] = {v0.x, v0.y, v0.z, v0.w, v1.x, v1.y, v1.z, v1.w};
                float ls = 0.f;
                #pragma unroll
                for (int j = 0; j < 8; ++j) {
                    float e = __expf(xv[j]);
                    o[j] = (short)f2bf(e);
                    ls += e;
                }
                atomicAdd(&sums[mi], ls);
            } else {
                #pragma unroll
                for (int j = 0; j < 8; ++j) o[j] = 0;
            }
            *(bf16x8*)(A + mi * 72 + j0) = o;
        }
        // B: features (NCHW fp32 -> bf16), rows = channels
        for (int s = 0; s < 8; ++s) {
            int q = tid + s * 256;
            int ci = q >> 3, j0 = (q & 7) * 8;
            const float4* sp4 = (const float4*)(feat + (long)(b * 256 + ci) * HW_ + k0 + j0);
            float4 v0 = sp4[0], v1 = sp4[1];
            float xv[8] = {v0.x, v0.y, v0.z, v0.w, v1.x, v1.y, v1.z, v1.w};
            bf16x8 o;
            #pragma unroll
            for (int j = 0; j < 8; ++j) o[j] = (short)f2bf(xv[j]);
            *(bf16x8*)(Bl + ci * 72 + j0) = o;
        }
        __syncthreads();
        #pragma unroll
        for (int kk = 0; kk < 64; kk += 32) {
            bf16x8 af[7], bfv[4];
            #pragma unroll
            for (int mf = 0; mf < 7; ++mf)
                af[mf] = *(const bf16x8*)(A + (mf * 16 + (lane & 15)) * 72 + kk + kgrp);
            #pragma unroll
            for (int nf = 0; nf < 4; ++nf)
                bfv[nf] = *(const bf16x8*)(Bl + (wq * 64 + nf * 16 + (lane & 15)) * 72 + kk + kgrp);
            #pragma unroll
            for (int mf = 0; mf < 7; ++mf)
                #pragma unroll
                for (int nf = 0; nf < 4; ++nf)
                    acc[mf][nf] = __builtin_amdgcn_mfma_f32_16x16x32_bf16(
                        af[mf], bfv[nf], acc[mf][nf], 0, 0, 0);
        }
        __syncthreads();
    }
    if (tid < 100) psum[(long)(b * 50 + slice) * 112 + tid] = sums[tid];
    float* dst = partials + (long)(b * 50 + slice) * 112 * 256;
    #pragma unroll
    for (int mf = 0; mf < 7; ++mf)
        #pragma unroll
        for (int nf = 0; nf < 4; ++nf) {
            int m0 = mf * 16 + ((lane >> 4) << 2);
            int c  = wq * 64 + nf * 16 + (lane & 15);
            #pragma unroll
            for (int j = 0; j < 4; ++j)
                dst[(long)(m0 + j) * 256 + c] = acc[mf][nf][j];
        }
}

// ---------------- sum partial slices + divide by denom -> inst_pool
__global__ __launch_bounds__(256) void k_redpool(const float* __restrict__ partials,
                                                 const float* __restrict__ psum,
                                                 float* __restrict__ inst_pool) {
    int bid = blockIdx.x;                       // b*100+m
    int b = bid / 100, m = bid - b * 100;
    int c = threadIdx.x;
    float s = 0.f, d = 0.f;
    for (int sl = 0; sl < 50; ++sl) {
        s += partials[((long)(b * 50 + sl) * 112 + m) * 256 + c];
        d += psum[(long)(b * 50 + sl) * 112 + m];
    }
    inst_pool[(long)bid * 256 + c] = s / d;
}

// ---------------- fc + relu + 4 heads (all fp32)
__global__ __launch_bounds__(256) void k_fc(const float* __restrict__ inst_pool,
                                            const float* __restrict__ w_fc, const float* __restrict__ b_fc,
                                            const float* __restrict__ w_cls, const float* __restrict__ b_cls,
                                            const float* __restrict__ w_ker, const float* __restrict__ b_ker,
                                            const float* __restrict__ w_obj, const float* __restrict__ b_obj,
                                            const float* __restrict__ w_box, const float* __restrict__ b_box,
                                            float* __restrict__ out) {
    int r = blockIdx.x;                         // 0..399
    int t = threadIdx.x;
    __shared__ float row[256];
    __shared__ float inst_s[256];
    row[t] = inst_pool[(long)r * 256 + t];
    __syncthreads();
    {
        float acc = b_fc[t];
        const float4* wv = (const float4*)(w_fc + (long)t * 256);
        for (int c = 0; c < 64; ++c) {
            float4 w4 = wv[c];
            acc += w4.x * row[c * 4] + w4.y * row[c * 4 + 1] + w4.z * row[c * 4 + 2] + w4.w * row[c * 4 + 3];
        }
        acc = fmaxf(acc, 0.f);
        inst_s[t] = acc;
        out[10376800 + (long)r * 256 + t] = acc;   // inst
    }
    __syncthreads();
    {
        float acc = b_ker[t];
        const float4* wv = (const float4*)(w_ker + (long)t * 256);
        for (int c = 0; c < 64; ++c) {
            float4 w4 = wv[c];
            acc += w4.x * inst_s[c * 4] + w4.y * inst_s[c * 4 + 1] + w4.z * inst_s[c * 4 + 2] + w4.w * inst_s[c * 4 + 3];
        }
        out[32400 + (long)r * 256 + t] = acc;      // pred_kernel
    }
    if (t < 81) {
        float acc = b_cls[t];
        const float4* wv = (const float4*)(w_cls + (long)t * 256);
        for (int c = 0; c < 64; ++c) {
            float4 w4 = wv[c];
            acc += w4.x * inst_s[c * 4] + w4.y * inst_s[c * 4 + 1] + w4.z * inst_s[c * 4 + 2] + w4.w * inst_s[c * 4 + 3];
        }
        out[(long)r * 81 + t] = acc;               // pred_logits
    }
    if (t == 0) {
        float acc = b_obj[0];
        for (int c = 0; c < 256; ++c) acc += w_obj[c] * inst_s[c];
        out[134800 + r] = acc;                     // pred_scores
    }
    if (t >= 1 && t < 5) {
        int j = t - 1;
        float acc = b_box[j];
        for (int c = 0; c < 256; ++c) acc += w_box[j * 256 + c] * inst_s[c];
        out[135200 + (long)r * 4 + j] = acc;       // pred_bboxes
    }
}

extern "C" void kernel_launch(void* const* d_in, const int* in_sizes, int n_in,
                              void* d_out, int out_size, void* d_ws, size_t ws_size,
                              hipStream_t stream) {
    const float* feat  = (const float*)d_in[0];
    const float* w_iam = (const float*)d_in[1];
    const float* b_iam = (const float*)d_in[2];
    // d_in[3] softmax_bias: uniform shift inside softmax -> cancels exactly
    const float* w_fc  = (const float*)d_in[4];
    const float* b_fc  = (const float*)d_in[5];
    const float* w_cls = (const float*)d_in[6];
    const float* b_cls = (const float*)d_in[7];
    const float* w_ker = (const float*)d_in[8];
    const float* b_ker = (const float*)d_in[9];
    const float* w_obj = (const float*)d_in[10];
    const float* b_obj = (const float*)d_in[11];
    const float* w_box = (const float*)d_in[12];
    const float* b_box = (const float*)d_in[13];
    float* out = (float*)d_out;

    char* ws = (char*)d_ws;
    unsigned short* fpad  = (unsigned short*)ws;               // 53,747,712 B
    unsigned short* wprep = (unsigned short*)(ws + 53747712);  //    589,824 B -> end 54,337,536
    // post-conv phase aliases fpad (dead after k_conv):
    float* partials  = (float*)ws;                             // 22,937,600 B
    float* psum      = (float*)(ws + 22937600);                //     89,600 B
    float* inst_pool = (float*)(ws + 23027200);                //    409,600 B

    float* iam = out + 136800;

    k_prepw  <<<dim3(1152), dim3(256), 0, stream>>>(w_iam, wprep);
    k_border <<<dim3(2576), dim3(256), 0, stream>>>(fpad);
    k_convert<<<dim3(2560), dim3(256), 0, stream>>>(feat, fpad);
    k_conv   <<<dim3(800),  dim3(256), 0, stream>>>(fpad, wprep, b_iam, iam);
    k_pool   <<<dim3(200),  dim3(256), 0, stream>>>(feat, iam, partials, psum);
    k_redpool<<<dim3(400),  dim3(256), 0, stream>>>(partials, psum, inst_pool);
    k_fc     <<<dim3(400),  dim3(256), 0, stream>>>(inst_pool, w_fc, b_fc, w_cls, b_cls,
                                                    w_ker, b_ker, w_obj, b_obj, w_box, b_box, out);
}